// Round 9
// baseline (234.184 us; speedup 1.0000x reference)
//
#include <hip/hip_runtime.h>
#include <math.h>

// Problem constants
#define B_TOT 2048
#define S_LEN 256
#define DIN   3
#define H     128
#define DOUT  6
#define DT_C  0.1f

#define NRB   4    // rows per GROUP; block = 2 groups = 8 rows
#define HPAD  136  // bf16 row stride in sh_h (128 + 8 pad)
#define PPAD  132  // f32 row stride in sh_p (head staging only)

// scale folded into W_hh/W_xh/b_hh so epilogue uses exp2 directly:
// tanh(p) = 1 - 2/(exp2(p * 2*log2e)+1)
#define PRESCALE 2.8853900817779268f   // 2*log2(e)

typedef __attribute__((ext_vector_type(8))) short short8;
typedef __attribute__((ext_vector_type(4))) float f32x4;

__device__ __forceinline__ unsigned short f2bf(float f) {
  unsigned int u = __float_as_uint(f);
  u += 0x7FFFu + ((u >> 16) & 1u);          // round-to-nearest-even
  return (unsigned short)(u >> 16);
}
__device__ __forceinline__ float bf2f(unsigned short h) {
  return __uint_as_float(((unsigned int)h) << 16);
}
__device__ __forceinline__ float bperm(int srcLane, float v) {
  return __int_as_float(__builtin_amdgcn_ds_bpermute(srcLane << 2, __float_as_int(v)));
}

// One block = 8 batch rows as TWO INDEPENDENT GROUPS of 4 (A: rows 0-3, B: rows 4-7),
// 512 threads (8 waves, 2/SIMD). Wave w owns j-tile [w*16, w*16+16) for both groups,
// sharing the same register-resident W fragments (PRESCALEd, hi/lo split).
// Per step, each group runs its own chain: ds_read(h) -> MFMA -> bperm -> epilogue
// -> ds_write(h'). The two chains are data-independent, so their latencies overlap
// within the same wave; ONE barrier per step covers both groups' h exchange.
//   MFMA (per group): D[m=j_loc][n=b], valid b = l16<4.
//   Epilogue: lane owns (b = lane&3, j = w*16 + (lane>>2)) -- 1 elem/group, dense.
__launch_bounds__(512, 2)
__global__ void ltc_kernel(const float* __restrict__ x,
                           const float* __restrict__ W_xh,
                           const float* __restrict__ W_hh,
                           const float* __restrict__ b_hh,
                           const float* __restrict__ log_tau,
                           const float* __restrict__ fc_W,
                           const float* __restrict__ fc_b,
                           float* __restrict__ out) {
  __shared__ alignas(16) unsigned short sh_h[2][2][NRB][HPAD];  // [pingpong][group][row][col]
  __shared__ alignas(16) float sh_p[2 * NRB][PPAD];             // final h fp32 for head

  const int tid  = threadIdx.x;
  const int w    = tid >> 6;        // wave 0..7 -> j-tile [w*16, w*16+16)
  const int lane = tid & 63;
  const int quad = lane >> 4;       // 0..3
  const int l16  = lane & 15;       // b-column in B/D fragments
  const int rb0  = blockIdx.x * (2 * NRB);

  // ---- zero both ping-pong buffers, both groups ----
  {
    uint4* p = (uint4*)&sh_h[0][0][0][0];
    const int n16 = (2 * 2 * NRB * HPAD) / 8;  // shorts -> uint4 count
    for (int i = tid; i < n16; i += 512) p[i] = make_uint4(0, 0, 0, 0);
  }

  // ---- W_hh A-fragments (hi/lo split of PRESCALE*W), shared by both groups ----
  // A[m=l16][k = kc*32 + quad*8 + i],  j = w*16 + m
  short8 wa_hi[4], wa_lo[4];
  {
    const int j = w * 16 + l16;
#pragma unroll
    for (int kc = 0; kc < 4; ++kc) {
      const float* src = W_hh + j * H + kc * 32 + quad * 8;
#pragma unroll
      for (int i = 0; i < 8; ++i) {
        float wv = src[i] * PRESCALE;
        unsigned short hi = f2bf(wv);
        unsigned short lo = f2bf(wv - bf2f(hi));   // hi+lo == wv to ~fp32 precision
        wa_hi[kc][i] = (short)hi;
        wa_lo[kc][i] = (short)lo;
      }
    }
  }

  // ---- epilogue mapping: lane owns (b = lane&3, j = w*16 + lane>>2), same j both groups ----
  const int eb = lane & 3;
  const int jl = lane >> 2;               // 0..15
  const int ej = w * 16 + jl;
  float ewx0, ewx1, ewx2, ebh, ecc, ea, encc2;
  {
    ewx0 = W_xh[ej * 3 + 0] * PRESCALE;
    ewx1 = W_xh[ej * 3 + 1] * PRESCALE;
    ewx2 = W_xh[ej * 3 + 2] * PRESCALE;
    ebh  = b_hh[ej] * PRESCALE;
    float lt  = log_tau[ej];
    float tau = logf(1.f + expf(lt)) + 0.001f;   // softplus + eps, exact fp32, once
    ecc   = DT_C / tau;
    ea    = 1.f - ecc;
    encc2 = -2.f * ecc;
  }
  const float* xpA = x + (size_t)(rb0 + eb) * (S_LEN * DIN);
  const float* xpB = xpA + (size_t)NRB * (S_LEN * DIN);

  float hA = 0.f, hB = 0.f;  // fp32 h for (eb, ej), register-resident

  // redistribution: preact (jl, eb) sits at lane (jl>>2)*16 + eb, reg jl&3
  const int srcLane = ((jl >> 2) << 4) | eb;
  const int rsel    = jl & 3;

  // static LDS offsets (shorts, within one group buffer)
  const int rd_off = l16 * HPAD + quad * 8;     // B-frag read base (+ kc*32), l16<4 only
  const int wr_off = eb * HPAD + w * 16 + jl;
  const unsigned short* __restrict__ bufA0 = &sh_h[0][0][0][0];
  unsigned short* __restrict__ bufA1 = &sh_h[1][0][0][0];
  const unsigned short* __restrict__ bufB0 = &sh_h[0][1][0][0];
  unsigned short* __restrict__ bufB1 = &sh_h[1][1][0][0];

  // persistent B-frag regs: zeroed ONCE; lanes l16>=4 never overwrite them
  short8 bfA[4], bfB[4];
#pragma unroll
  for (int kc = 0; kc < 4; ++kc) {
    bfA[kc] = short8{0, 0, 0, 0, 0, 0, 0, 0};
    bfB[kc] = short8{0, 0, 0, 0, 0, 0, 0, 0};
  }

  // x prefetch: 6 floats per 2-step pair as 3x float2 per group
  float2 pA0 = *(const float2*)(xpA), pA1 = *(const float2*)(xpA + 2), pA2 = *(const float2*)(xpA + 4);
  float2 pB0 = *(const float2*)(xpB), pB1 = *(const float2*)(xpB + 2), pB2 = *(const float2*)(xpB + 4);

  __syncthreads();

  auto do_step = [&](const unsigned short* __restrict__ curA, unsigned short* __restrict__ nxtA,
                     const unsigned short* __restrict__ curB, unsigned short* __restrict__ nxtB,
                     float xA0, float xA1, float xA2, float xB0, float xB1, float xB2) {
    // x-projection terms (independent of LDS/MFMA)
    float tA = __builtin_fmaf(xA2, ewx2, ebh);
    tA = __builtin_fmaf(xA1, ewx1, tA);
    tA = __builtin_fmaf(xA0, ewx0, tA);
    float tB = __builtin_fmaf(xB2, ewx2, ebh);
    tB = __builtin_fmaf(xB1, ewx1, tB);
    tB = __builtin_fmaf(xB0, ewx0, tB);

    // B-fragments of both groups' h (masked; lanes l16>=4 keep zeros)
    if (l16 < NRB) {
#pragma unroll
      for (int kc = 0; kc < 4; ++kc) {
        bfA[kc] = *(const short8*)(curA + rd_off + kc * 32);
        bfB[kc] = *(const short8*)(curB + rd_off + kc * 32);
      }
    }

    // 4 independent 4-deep MFMA chains (2 groups x hi/lo)
    f32x4 ahA = {0.f,0.f,0.f,0.f}, alA = {0.f,0.f,0.f,0.f};
    f32x4 ahB = {0.f,0.f,0.f,0.f}, alB = {0.f,0.f,0.f,0.f};
#pragma unroll
    for (int kc = 0; kc < 4; ++kc) {
      ahA = __builtin_amdgcn_mfma_f32_16x16x32_bf16(wa_hi[kc], bfA[kc], ahA, 0, 0, 0);
      ahB = __builtin_amdgcn_mfma_f32_16x16x32_bf16(wa_hi[kc], bfB[kc], ahB, 0, 0, 0);
      alA = __builtin_amdgcn_mfma_f32_16x16x32_bf16(wa_lo[kc], bfA[kc], alA, 0, 0, 0);
      alB = __builtin_amdgcn_mfma_f32_16x16x32_bf16(wa_lo[kc], bfB[kc], alB, 0, 0, 0);
    }

    // intra-wave redistribution: bperm all 4 regs, then select by rsel
    float a0 = bperm(srcLane, ahA[0] + alA[0]);
    float a1 = bperm(srcLane, ahA[1] + alA[1]);
    float a2 = bperm(srcLane, ahA[2] + alA[2]);
    float a3 = bperm(srcLane, ahA[3] + alA[3]);
    float b0 = bperm(srcLane, ahB[0] + alB[0]);
    float b1 = bperm(srcLane, ahB[1] + alB[1]);
    float b2 = bperm(srcLane, ahB[2] + alB[2]);
    float b3 = bperm(srcLane, ahB[3] + alB[3]);
    float cA01 = (rsel & 1) ? a1 : a0;
    float cA23 = (rsel & 1) ? a3 : a2;
    float pA   = (rsel & 2) ? cA23 : cA01;
    float cB01 = (rsel & 1) ? b1 : b0;
    float cB23 = (rsel & 1) ? b3 : b2;
    float pB   = (rsel & 2) ? cB23 : cB01;

    // epilogue (PRESCALEd): f = 1 - 2/(exp2(p+t)+1); h' = h*(1-cc) + cc*f
    {
      float e  = __builtin_amdgcn_exp2f(pA + tA);
      float rc = __builtin_amdgcn_rcpf(e + 1.f);
      hA = __builtin_fmaf(encc2, rc, __builtin_fmaf(hA, ea, ecc));
    }
    {
      float e  = __builtin_amdgcn_exp2f(pB + tB);
      float rc = __builtin_amdgcn_rcpf(e + 1.f);
      hB = __builtin_fmaf(encc2, rc, __builtin_fmaf(hB, ea, ecc));
    }

    nxtA[wr_off] = f2bf(hA);   // 2B store, distinct (b,j) per lane
    nxtB[wr_off] = f2bf(hB);
    __syncthreads();
  };

  for (int s = 0; s < S_LEN; s += 2) {
    float2 a0 = pA0, a1 = pA1, a2 = pA2;
    float2 b0 = pB0, b1 = pB1, b2 = pB2;
    if (s + 2 < S_LEN) {           // uniform branch; prefetch next pair
      xpA += 6; xpB += 6;
      pA0 = *(const float2*)(xpA); pA1 = *(const float2*)(xpA + 2); pA2 = *(const float2*)(xpA + 4);
      pB0 = *(const float2*)(xpB); pB1 = *(const float2*)(xpB + 2); pB2 = *(const float2*)(xpB + 4);
    }
    do_step(bufA0, bufA1, bufB0, bufB1, a0.x, a0.y, a1.x, b0.x, b0.y, b1.x);
    do_step(bufA1, (unsigned short*)bufA0, bufB1, (unsigned short*)bufB0,
            a1.y, a2.x, a2.y, b1.y, b2.x, b2.y);
  }

  // ---- final head: params = softplus(h @ fc_W^T + fc_b), [8 x 6] per block ----
  sh_p[eb][ej]       = hA;
  sh_p[NRB + eb][ej] = hB;
  __syncthreads();

  if (tid < 2 * NRB * DOUT) {
    const int b = tid / DOUT;
    const int o = tid - b * DOUT;
    const float* fw = fc_W + o * H;
    float acc = fc_b[o];
#pragma unroll 4
    for (int k = 0; k < H; ++k) acc += sh_p[b][k] * fw[k];
    float sp = (acc > 15.f) ? acc : logf(1.f + expf(acc));
    out[(rb0 + b) * DOUT + o] = sp;
  }
}

extern "C" void kernel_launch(void* const* d_in, const int* in_sizes, int n_in,
                              void* d_out, int out_size, void* d_ws, size_t ws_size,
                              hipStream_t stream) {
  const float* x       = (const float*)d_in[0];
  const float* W_xh    = (const float*)d_in[1];
  const float* W_hh    = (const float*)d_in[2];
  const float* b_hh    = (const float*)d_in[3];
  const float* log_tau = (const float*)d_in[4];
  const float* fc_W    = (const float*)d_in[5];
  const float* fc_b    = (const float*)d_in[6];
  float* out           = (float*)d_out;

  ltc_kernel<<<dim3(B_TOT / (2 * NRB)), dim3(512), 0, stream>>>(
      x, W_xh, W_hh, b_hh, log_tau, fc_W, fc_b, out);
}

// Round 10
// 164.532 us; speedup vs baseline: 1.4233x; 1.4233x over previous
//
#include <hip/hip_runtime.h>
#include <math.h>

// Problem constants
#define B_TOT 2048
#define S_LEN 256
#define DIN   3
#define H     128
#define DOUT  6
#define DT_C  0.1f

#define NROWS 8    // batch rows per block (valid cols of the n=16 MFMA face)
#define HPAD  136  // bf16 row stride in sh_h (128 + 8 pad), rows 16B-aligned
#define PPAD  132  // f32 row stride in sh_p (head staging only)

// scale folded into W_hh/W_xh/b_hh so epilogue uses exp2 directly:
// tanh(p) = 1 - 2/(exp2(p * 2*log2e)+1)
#define PRESCALE 2.8853900817779268f   // 2*log2(e)

typedef __attribute__((ext_vector_type(8))) short short8;
typedef __attribute__((ext_vector_type(4))) float f32x4;
typedef __attribute__((ext_vector_type(2))) unsigned int u32x2;

__device__ __forceinline__ unsigned short f2bf(float f) {
  unsigned int u = __float_as_uint(f);
  u += 0x7FFFu + ((u >> 16) & 1u);          // round-to-nearest-even
  return (unsigned short)(u >> 16);
}
__device__ __forceinline__ float bf2f(unsigned short h) {
  return __uint_as_float(((unsigned int)h) << 16);
}
// pack two f32 -> two bf16 (RNE) in one dword
__device__ __forceinline__ unsigned int pack2_bf16(float a, float b) {
  unsigned int ua = __float_as_uint(a), ub = __float_as_uint(b);
  ua = ua + 0x7FFFu + ((ua >> 16) & 1u);
  ub = ub + 0x7FFFu + ((ub >> 16) & 1u);
  return (ua >> 16) | (ub & 0xFFFF0000u);
}

// One block = 8 batch rows, 512 threads (8 waves, 2/SIMD). Wave w owns j-tile
// [w*16, w*16+16); A = W_hh rows (PRESCALEd, hi/lo split, register-resident).
//   MFMA: D[m=j_loc][n=b] ; lane holds (b = lane&15, j_loc = quad*4 + r).
// Epilogue runs DIRECTLY in D-fragment layout on valid lanes (b = l16 < 8):
// each valid lane owns 4 elems (b, j = w*16+quad*4+{0..3}) — no bperm, no staging.
// B-frag LDS reads exec-masked to l16<8; masked-out lanes keep once-zeroed regs.
// ONE barrier per step; ping-pong h buffers; step pair shares float2 x loads.
__launch_bounds__(512, 2)
__global__ void ltc_kernel(const float* __restrict__ x,
                           const float* __restrict__ W_xh,
                           const float* __restrict__ W_hh,
                           const float* __restrict__ b_hh,
                           const float* __restrict__ log_tau,
                           const float* __restrict__ fc_W,
                           const float* __restrict__ fc_b,
                           float* __restrict__ out) {
  __shared__ alignas(16) unsigned short sh_h[2][NROWS][HPAD];  // ping-pong h bf16
  __shared__ alignas(16) float sh_p[NROWS][PPAD];              // final h fp32 for head

  const int tid  = threadIdx.x;
  const int w    = tid >> 6;        // wave 0..7 -> j-tile [w*16, w*16+16)
  const int lane = tid & 63;
  const int quad = lane >> 4;       // 0..3
  const int l16  = lane & 15;       // b-column in B/D fragments
  const int rb0  = blockIdx.x * NROWS;

  // ---- zero both h buffers ----
  {
    uint4* p = (uint4*)&sh_h[0][0][0];
    const int n16 = (2 * NROWS * HPAD) / 8;  // shorts -> uint4 count
    for (int i = tid; i < n16; i += 512) p[i] = make_uint4(0, 0, 0, 0);
  }

  // ---- W_hh A-fragments (hi/lo split of PRESCALE*W), register-resident ----
  // A[m=l16][k = kc*32 + quad*8 + i],  j = w*16 + m
  short8 wa_hi[4], wa_lo[4];
  {
    const int j = w * 16 + l16;
#pragma unroll
    for (int kc = 0; kc < 4; ++kc) {
      const float* src = W_hh + j * H + kc * 32 + quad * 8;
#pragma unroll
      for (int i = 0; i < 8; ++i) {
        float wv = src[i] * PRESCALE;
        unsigned short hi = f2bf(wv);
        unsigned short lo = f2bf(wv - bf2f(hi));   // hi+lo == wv to ~fp32 precision
        wa_hi[kc][i] = (short)hi;
        wa_lo[kc][i] = (short)lo;
      }
    }
  }

  // ---- epilogue constants for this lane's 4 j's (j = w*16 + quad*4 + r) ----
  // Constants depend only on j -> identical across the 16 b-columns; valid on all lanes.
  float ewx[4][3], ebh[4], ecc[4], ea[4], encc2[4];
#pragma unroll
  for (int r = 0; r < 4; ++r) {
    const int j = w * 16 + quad * 4 + r;
    ewx[r][0] = W_xh[j * 3 + 0] * PRESCALE;
    ewx[r][1] = W_xh[j * 3 + 1] * PRESCALE;
    ewx[r][2] = W_xh[j * 3 + 2] * PRESCALE;
    ebh[r]    = b_hh[j] * PRESCALE;
    float lt  = log_tau[j];
    float tau = logf(1.f + expf(lt)) + 0.001f;   // softplus + eps, exact fp32, once
    float cc  = DT_C / tau;
    ecc[r]    = cc;
    ea[r]     = 1.f - cc;
    encc2[r]  = -2.f * cc;
  }

  // epilogue validity & x stream: valid lane owns batch row b = l16
  const bool valid = (l16 < NROWS);
  const int  brow  = l16 & (NROWS - 1);
  const float* xp  = x + (size_t)(rb0 + brow) * (S_LEN * DIN);

  float hreg[4] = {0.f, 0.f, 0.f, 0.f};  // fp32 h for (b=l16, j..j+3), register-resident

  // static LDS offsets (shorts)
  const int rd_off = l16 * HPAD + quad * 8;          // B-frag read base (+ kc*32), l16<8 only
  const int wr_off = l16 * HPAD + w * 16 + quad * 4; // h' write (valid lanes), 8B aligned
  const unsigned short* __restrict__ buf0 = &sh_h[0][0][0];
  unsigned short* __restrict__ buf1 = &sh_h[1][0][0];

  // persistent B-frag regs: zeroed ONCE; lanes l16>=8 never overwrite them
  short8 bf[4];
#pragma unroll
  for (int kc = 0; kc < 4; ++kc) bf[kc] = short8{0, 0, 0, 0, 0, 0, 0, 0};

  // x prefetch: 6 floats per 2-step pair as 3x float2 (24B step-pair stride)
  float2 pfa = *(const float2*)(xp);
  float2 pfb = *(const float2*)(xp + 2);
  float2 pfc = *(const float2*)(xp + 4);

  __syncthreads();

  auto do_step = [&](const unsigned short* __restrict__ cur,
                     unsigned short* __restrict__ nxt,
                     float xc0, float xc1, float xc2) {
    // B-fragments of h^T (masked; lanes >=8 keep zeros)
    if (l16 < NROWS) {
#pragma unroll
      for (int kc = 0; kc < 4; ++kc)
        bf[kc] = *(const short8*)(cur + rd_off + kc * 32);
    }

    // x-projection terms (independent of LDS/MFMA; hidden under ds_read latency)
    float t[4];
#pragma unroll
    for (int r = 0; r < 4; ++r) {
      float tt = __builtin_fmaf(xc2, ewx[r][2], ebh[r]);
      tt = __builtin_fmaf(xc1, ewx[r][1], tt);
      t[r] = __builtin_fmaf(xc0, ewx[r][0], tt);
    }

    // two independent 4-deep MFMA chains (hi/lo W split)
    f32x4 ah = {0.f, 0.f, 0.f, 0.f};
    f32x4 al = {0.f, 0.f, 0.f, 0.f};
#pragma unroll
    for (int kc = 0; kc < 4; ++kc) {
      ah = __builtin_amdgcn_mfma_f32_16x16x32_bf16(wa_hi[kc], bf[kc], ah, 0, 0, 0);
      al = __builtin_amdgcn_mfma_f32_16x16x32_bf16(wa_lo[kc], bf[kc], al, 0, 0, 0);
    }

    // epilogue directly in D layout (valid lanes: b = l16, 4 j's per lane)
    if (valid) {
#pragma unroll
      for (int r = 0; r < 4; ++r) {
        float pre = (ah[r] + al[r]) + t[r];
        float e   = __builtin_amdgcn_exp2f(pre);
        float rc  = __builtin_amdgcn_rcpf(e + 1.f);
        hreg[r] = __builtin_fmaf(encc2[r], rc, __builtin_fmaf(hreg[r], ea[r], ecc[r]));
      }
      u32x2 hv;
      hv.x = pack2_bf16(hreg[0], hreg[1]);
      hv.y = pack2_bf16(hreg[2], hreg[3]);
      *(u32x2*)(nxt + wr_off) = hv;   // 8B store, row b, 4 consecutive j
    }
    __syncthreads();
  };

  for (int s = 0; s < S_LEN; s += 2) {
    float2 xa = pfa, xb = pfb, xc = pfc;
    if (s + 2 < S_LEN) {           // uniform branch; prefetch next pair
      xp += 6;
      pfa = *(const float2*)(xp);
      pfb = *(const float2*)(xp + 2);
      pfc = *(const float2*)(xp + 4);
    }
    do_step(buf0, buf1, xa.x, xa.y, xb.x);
    do_step(buf1, (unsigned short*)buf0, xb.y, xc.x, xc.y);
  }

  // ---- final head: params = softplus(h @ fc_W^T + fc_b), [8 x 6] per block ----
  if (valid) {
    f32x4 v = {hreg[0], hreg[1], hreg[2], hreg[3]};
    *(f32x4*)&sh_p[brow][w * 16 + quad * 4] = v;   // 16B-aligned (col multiple of 4)
  }
  __syncthreads();

  if (tid < NROWS * DOUT) {
    const int b = tid / DOUT;
    const int o = tid - b * DOUT;
    const float* fw = fc_W + o * H;
    float acc = fc_b[o];
#pragma unroll 4
    for (int k = 0; k < H; ++k) acc += sh_p[b][k] * fw[k];
    float sp = (acc > 15.f) ? acc : logf(1.f + expf(acc));
    out[(rb0 + b) * DOUT + o] = sp;
  }
}

extern "C" void kernel_launch(void* const* d_in, const int* in_sizes, int n_in,
                              void* d_out, int out_size, void* d_ws, size_t ws_size,
                              hipStream_t stream) {
  const float* x       = (const float*)d_in[0];
  const float* W_xh    = (const float*)d_in[1];
  const float* W_hh    = (const float*)d_in[2];
  const float* b_hh    = (const float*)d_in[3];
  const float* log_tau = (const float*)d_in[4];
  const float* fc_W    = (const float*)d_in[5];
  const float* fc_b    = (const float*)d_in[6];
  float* out           = (float*)d_out;

  ltc_kernel<<<dim3(B_TOT / NROWS), dim3(512), 0, stream>>>(
      x, W_xh, W_hh, b_hh, log_tau, fc_W, fc_b, out);
}

// Round 11
// 157.376 us; speedup vs baseline: 1.4881x; 1.0455x over previous
//
#include <hip/hip_runtime.h>
#include <math.h>

// Problem constants
#define B_TOT 2048
#define S_LEN 256
#define DIN   3
#define H     128
#define DOUT  6
#define DT_C  0.1f

#define NROWS 8    // batch rows per block (valid cols of the n=16 MFMA face)
#define HPAD  136  // bf16 row stride in sh_h (128 + 8 pad), rows 16B-aligned
#define PPAD  132  // f32 row stride in sh_p (head staging only)

// scale folded into W_hh/W_xh/b_hh so epilogue uses exp2 directly:
// tanh(p) = 1 - 2/(exp2(p * 2*log2e)+1)
#define PRESCALE 2.8853900817779268f   // 2*log2(e)

typedef __attribute__((ext_vector_type(8))) short short8;
typedef __attribute__((ext_vector_type(4))) float f32x4;

__device__ __forceinline__ unsigned short f2bf(float f) {
  unsigned int u = __float_as_uint(f);
  u += 0x7FFFu + ((u >> 16) & 1u);          // round-to-nearest-even
  return (unsigned short)(u >> 16);
}
__device__ __forceinline__ float bf2f(unsigned short h) {
  return __uint_as_float(((unsigned int)h) << 16);
}
// pack two f32 -> two bf16 (RNE) in one dword
__device__ __forceinline__ unsigned int pack2_bf16(float a, float b) {
  unsigned int ua = __float_as_uint(a), ub = __float_as_uint(b);
  ua = ua + 0x7FFFu + ((ua >> 16) & 1u);
  ub = ub + 0x7FFFu + ((ub >> 16) & 1u);
  return (ua >> 16) | (ub & 0xFFFF0000u);
}
// lane-pair exchange lane <-> lane^8 within 16-lane DPP row (full-rate VALU, no LDS)
__device__ __forceinline__ float dpp_xor8(float v) {
  int i = __float_as_int(v);
  int r = __builtin_amdgcn_update_dpp(i, i, 0x128 /*row_ror:8*/, 0xF, 0xF, false);
  return __int_as_float(r);
}

// One block = 8 batch rows, 512 threads (8 waves, 2/SIMD). Wave w owns j-tile
// [w*16, w*16+16); A = W_hh rows (PRESCALEd, hi/lo split, register-resident).
//   MFMA: D[m=j_loc][n=b] ; lane holds (b = lane&15, j_loc = quad*4 + r).
// DENSE epilogue via DPP: lane b keeps regs r=0,1; partner lane b+8 receives
// r=2,3 via row_ror:8 (same 16-lane row). Every lane owns 2 elems
// (b = l16&7, j = w*16 + quad*4 + (l16>>3)*2 + {0,1}) for all 256 steps:
// half the transcendental wave-ops of the masked version, dense 4B h-stores.
// B-frag LDS reads exec-masked to l16<8; masked-out lanes keep once-zeroed regs.
// ONE barrier per step; ping-pong h buffers; step pair shares float2 x loads.
__launch_bounds__(512, 2)
__global__ void ltc_kernel(const float* __restrict__ x,
                           const float* __restrict__ W_xh,
                           const float* __restrict__ W_hh,
                           const float* __restrict__ b_hh,
                           const float* __restrict__ log_tau,
                           const float* __restrict__ fc_W,
                           const float* __restrict__ fc_b,
                           float* __restrict__ out) {
  __shared__ alignas(16) unsigned short sh_h[2][NROWS][HPAD];  // ping-pong h bf16
  __shared__ alignas(16) float sh_p[NROWS][PPAD];              // final h fp32 for head

  const int tid  = threadIdx.x;
  const int w    = tid >> 6;        // wave 0..7 -> j-tile [w*16, w*16+16)
  const int lane = tid & 63;
  const int quad = lane >> 4;       // 0..3
  const int l16  = lane & 15;       // b-column in B/D fragments
  const int rb0  = blockIdx.x * NROWS;

  // ---- zero both h buffers ----
  {
    uint4* p = (uint4*)&sh_h[0][0][0];
    const int n16 = (2 * NROWS * HPAD) / 8;  // shorts -> uint4 count
    for (int i = tid; i < n16; i += 512) p[i] = make_uint4(0, 0, 0, 0);
  }

  // ---- W_hh A-fragments (hi/lo split of PRESCALE*W), register-resident ----
  // A[m=l16][k = kc*32 + quad*8 + i],  j = w*16 + m
  short8 wa_hi[4], wa_lo[4];
  {
    const int j = w * 16 + l16;
#pragma unroll
    for (int kc = 0; kc < 4; ++kc) {
      const float* src = W_hh + j * H + kc * 32 + quad * 8;
#pragma unroll
      for (int i = 0; i < 8; ++i) {
        float wv = src[i] * PRESCALE;
        unsigned short hi = f2bf(wv);
        unsigned short lo = f2bf(wv - bf2f(hi));   // hi+lo == wv to ~fp32 precision
        wa_hi[kc][i] = (short)hi;
        wa_lo[kc][i] = (short)lo;
      }
    }
  }

  // ---- dense epilogue mapping: lane owns (b = l16&7, j = w*16+quad*4+(l16>>3)*2+{0,1}) ----
  const int brow = l16 & 7;
  const int rbse = (l16 >> 3) * 2;            // 0 for lanes b, 2 for partner lanes b+8
  float ewx[2][3], ebh[2], ecc[2], ea[2], encc2[2];
#pragma unroll
  for (int r = 0; r < 2; ++r) {
    const int j = w * 16 + quad * 4 + rbse + r;
    ewx[r][0] = W_xh[j * 3 + 0] * PRESCALE;
    ewx[r][1] = W_xh[j * 3 + 1] * PRESCALE;
    ewx[r][2] = W_xh[j * 3 + 2] * PRESCALE;
    ebh[r]    = b_hh[j] * PRESCALE;
    float lt  = log_tau[j];
    float tau = logf(1.f + expf(lt)) + 0.001f;   // softplus + eps, exact fp32, once
    float cc  = DT_C / tau;
    ecc[r]    = cc;
    ea[r]     = 1.f - cc;
    encc2[r]  = -2.f * cc;
  }
  const bool lowhalf = (l16 < 8);
  const float* xp = x + (size_t)(rb0 + brow) * (S_LEN * DIN);

  float hreg[2] = {0.f, 0.f};  // fp32 h for (brow, j..j+1), register-resident

  // static LDS offsets (shorts)
  const int rd_off = l16 * HPAD + quad * 8;                     // B-frag read (+ kc*32), l16<8
  const int wr_off = brow * HPAD + w * 16 + quad * 4 + rbse;    // dense 4B h' store
  const unsigned short* __restrict__ buf0 = &sh_h[0][0][0];
  unsigned short* __restrict__ buf1 = &sh_h[1][0][0];

  // persistent B-frag regs: zeroed ONCE; lanes l16>=8 never overwrite them
  short8 bf[4];
#pragma unroll
  for (int kc = 0; kc < 4; ++kc) bf[kc] = short8{0, 0, 0, 0, 0, 0, 0, 0};

  // x prefetch: 6 floats per 2-step pair as 3x float2 (24B step-pair stride)
  float2 pfa = *(const float2*)(xp);
  float2 pfb = *(const float2*)(xp + 2);
  float2 pfc = *(const float2*)(xp + 4);

  __syncthreads();

  auto do_step = [&](const unsigned short* __restrict__ cur,
                     unsigned short* __restrict__ nxt,
                     float xc0, float xc1, float xc2) {
    // B-fragments of h^T (masked; lanes >=8 keep zeros)
    if (l16 < NROWS) {
#pragma unroll
      for (int kc = 0; kc < 4; ++kc)
        bf[kc] = *(const short8*)(cur + rd_off + kc * 32);
    }

    // x-projection terms for this lane's 2 elems (hidden under ds_read latency)
    float t0 = __builtin_fmaf(xc2, ewx[0][2], ebh[0]);
    t0 = __builtin_fmaf(xc1, ewx[0][1], t0);
    t0 = __builtin_fmaf(xc0, ewx[0][0], t0);
    float t1 = __builtin_fmaf(xc2, ewx[1][2], ebh[1]);
    t1 = __builtin_fmaf(xc1, ewx[1][1], t1);
    t1 = __builtin_fmaf(xc0, ewx[1][0], t1);

    // two independent 4-deep MFMA chains (hi/lo W split)
    f32x4 ah = {0.f, 0.f, 0.f, 0.f};
    f32x4 al = {0.f, 0.f, 0.f, 0.f};
#pragma unroll
    for (int kc = 0; kc < 4; ++kc) {
      ah = __builtin_amdgcn_mfma_f32_16x16x32_bf16(wa_hi[kc], bf[kc], ah, 0, 0, 0);
      al = __builtin_amdgcn_mfma_f32_16x16x32_bf16(wa_lo[kc], bf[kc], al, 0, 0, 0);
    }
    float s0 = ah[0] + al[0];
    float s1 = ah[1] + al[1];
    float s2 = ah[2] + al[2];
    float s3 = ah[3] + al[3];

    // DPP pair-exchange: partner lanes (l16>=8) receive r=2,3 from lane l16-8
    float d2 = dpp_xor8(s2);
    float d3 = dpp_xor8(s3);
    float pre0 = lowhalf ? s0 : d2;
    float pre1 = lowhalf ? s1 : d3;

    // dense epilogue: 2 elems/lane, every lane
    {
      float e  = __builtin_amdgcn_exp2f(pre0 + t0);
      float rc = __builtin_amdgcn_rcpf(e + 1.f);
      hreg[0] = __builtin_fmaf(encc2[0], rc, __builtin_fmaf(hreg[0], ea[0], ecc[0]));
    }
    {
      float e  = __builtin_amdgcn_exp2f(pre1 + t1);
      float rc = __builtin_amdgcn_rcpf(e + 1.f);
      hreg[1] = __builtin_fmaf(encc2[1], rc, __builtin_fmaf(hreg[1], ea[1], ecc[1]));
    }

    *(unsigned int*)(nxt + wr_off) = pack2_bf16(hreg[0], hreg[1]);  // dense 4B store
    __syncthreads();
  };

  for (int s = 0; s < S_LEN; s += 2) {
    float2 xa = pfa, xb = pfb, xc = pfc;
    if (s + 2 < S_LEN) {           // uniform branch; prefetch next pair
      xp += 6;
      pfa = *(const float2*)(xp);
      pfb = *(const float2*)(xp + 2);
      pfc = *(const float2*)(xp + 4);
    }
    do_step(buf0, buf1, xa.x, xa.y, xb.x);
    do_step(buf1, (unsigned short*)buf0, xb.y, xc.x, xc.y);
  }

  // ---- final head: params = softplus(h @ fc_W^T + fc_b), [8 x 6] per block ----
  {
    float2 v = make_float2(hreg[0], hreg[1]);
    *(float2*)&sh_p[brow][w * 16 + quad * 4 + rbse] = v;   // 8B-aligned, all lanes distinct
  }
  __syncthreads();

  if (tid < NROWS * DOUT) {
    const int b = tid / DOUT;
    const int o = tid - b * DOUT;
    const float* fw = fc_W + o * H;
    float acc = fc_b[o];
#pragma unroll 4
    for (int k = 0; k < H; ++k) acc += sh_p[b][k] * fw[k];
    float sp = (acc > 15.f) ? acc : logf(1.f + expf(acc));
    out[(rb0 + b) * DOUT + o] = sp;
  }
}

extern "C" void kernel_launch(void* const* d_in, const int* in_sizes, int n_in,
                              void* d_out, int out_size, void* d_ws, size_t ws_size,
                              hipStream_t stream) {
  const float* x       = (const float*)d_in[0];
  const float* W_xh    = (const float*)d_in[1];
  const float* W_hh    = (const float*)d_in[2];
  const float* b_hh    = (const float*)d_in[3];
  const float* log_tau = (const float*)d_in[4];
  const float* fc_W    = (const float*)d_in[5];
  const float* fc_b    = (const float*)d_in[6];
  float* out           = (float*)d_out;

  ltc_kernel<<<dim3(B_TOT / NROWS), dim3(512), 0, stream>>>(
      x, W_xh, W_hh, b_hh, log_tau, fc_W, fc_b, out);
}

// Round 12
// 145.095 us; speedup vs baseline: 1.6140x; 1.0846x over previous
//
#include <hip/hip_runtime.h>
#include <math.h>

// Problem constants
#define B_TOT 2048
#define S_LEN 256
#define DIN   3
#define H     128
#define DOUT  6
#define DT_C  0.1f

#define NROWS 8    // batch rows per block (valid cols of the n=16 MFMA face)
#define HPAD  136  // bf16 row stride in sh_h (128 + 8 pad), rows 16B-aligned
#define PPAD  132  // f32 row stride in sh_p (head staging only)

// scale folded into W_hh/W_xh/b_hh so epilogue uses exp2 directly:
// tanh(p) = 1 - 2/(exp2(p * 2*log2e)+1)
#define PRESCALE 2.8853900817779268f   // 2*log2(e)

typedef __attribute__((ext_vector_type(8))) short short8;
typedef __attribute__((ext_vector_type(4))) float f32x4;

__device__ __forceinline__ unsigned short f2bf(float f) {
  unsigned int u = __float_as_uint(f);
  u += 0x7FFFu + ((u >> 16) & 1u);          // round-to-nearest-even
  return (unsigned short)(u >> 16);
}
// pack two f32 -> two bf16 (RNE) in one dword
__device__ __forceinline__ unsigned int pack2_bf16(float a, float b) {
  unsigned int ua = __float_as_uint(a), ub = __float_as_uint(b);
  ua = ua + 0x7FFFu + ((ua >> 16) & 1u);
  ub = ub + 0x7FFFu + ((ub >> 16) & 1u);
  return (ua >> 16) | (ub & 0xFFFF0000u);
}
// lane-pair exchange lane <-> lane^8 within 16-lane DPP row (full-rate VALU, no LDS)
__device__ __forceinline__ float dpp_xor8(float v) {
  int i = __float_as_int(v);
  int r = __builtin_amdgcn_update_dpp(i, i, 0x128 /*row_ror:8*/, 0xF, 0xF, false);
  return __int_as_float(r);
}

// One block = 8 batch rows, 512 threads (8 waves, 2/SIMD). Wave w owns j-tile
// [w*16, w*16+16); A = W_hh rows (PRESCALEd, plain bf16 RNE, register-resident).
//   MFMA: D[m=j_loc][n=b] ; lane holds (b = lane&15, j_loc = quad*4 + r).
// DENSE epilogue via DPP: lane b keeps regs r=0,1; partner lane b+8 receives
// r=2,3 via row_ror:8. Every lane owns 2 elems
// (b = l16&7, j = w*16 + quad*4 + (l16>>3)*2 + {0,1}) for all 256 steps.
// B-frag LDS reads exec-masked to l16<8; masked-out lanes keep once-zeroed regs.
// ONE barrier per step; ping-pong h buffers; step pair shares float2 x loads.
// R12: dropped the Wlo correction MFMA chain (halves matrix-pipe time; error
// budget analysis says plain-bf16 W adds ~1e-3 to absmax, threshold 0.019).
__launch_bounds__(512, 2)
__global__ void ltc_kernel(const float* __restrict__ x,
                           const float* __restrict__ W_xh,
                           const float* __restrict__ W_hh,
                           const float* __restrict__ b_hh,
                           const float* __restrict__ log_tau,
                           const float* __restrict__ fc_W,
                           const float* __restrict__ fc_b,
                           float* __restrict__ out) {
  __shared__ alignas(16) unsigned short sh_h[2][NROWS][HPAD];  // ping-pong h bf16
  __shared__ alignas(16) float sh_p[NROWS][PPAD];              // final h fp32 for head

  const int tid  = threadIdx.x;
  const int w    = tid >> 6;        // wave 0..7 -> j-tile [w*16, w*16+16)
  const int lane = tid & 63;
  const int quad = lane >> 4;       // 0..3
  const int l16  = lane & 15;       // b-column in B/D fragments
  const int rb0  = blockIdx.x * NROWS;

  // ---- zero both h buffers ----
  {
    uint4* p = (uint4*)&sh_h[0][0][0];
    const int n16 = (2 * NROWS * HPAD) / 8;  // shorts -> uint4 count
    for (int i = tid; i < n16; i += 512) p[i] = make_uint4(0, 0, 0, 0);
  }

  // ---- W_hh A-fragments (PRESCALE*W, RNE bf16), register-resident ----
  // A[m=l16][k = kc*32 + quad*8 + i],  j = w*16 + m
  short8 wa[4];
  {
    const int j = w * 16 + l16;
#pragma unroll
    for (int kc = 0; kc < 4; ++kc) {
      const float* src = W_hh + j * H + kc * 32 + quad * 8;
#pragma unroll
      for (int i = 0; i < 8; ++i)
        wa[kc][i] = (short)f2bf(src[i] * PRESCALE);
    }
  }

  // ---- dense epilogue mapping: lane owns (b = l16&7, j = w*16+quad*4+(l16>>3)*2+{0,1}) ----
  const int brow = l16 & 7;
  const int rbse = (l16 >> 3) * 2;            // 0 for lanes b, 2 for partner lanes b+8
  float ewx[2][3], ebh[2], ecc[2], ea[2], encc2[2];
#pragma unroll
  for (int r = 0; r < 2; ++r) {
    const int j = w * 16 + quad * 4 + rbse + r;
    ewx[r][0] = W_xh[j * 3 + 0] * PRESCALE;
    ewx[r][1] = W_xh[j * 3 + 1] * PRESCALE;
    ewx[r][2] = W_xh[j * 3 + 2] * PRESCALE;
    ebh[r]    = b_hh[j] * PRESCALE;
    float lt  = log_tau[j];
    float tau = logf(1.f + expf(lt)) + 0.001f;   // softplus + eps, exact fp32, once
    float cc  = DT_C / tau;
    ecc[r]    = cc;
    ea[r]     = 1.f - cc;
    encc2[r]  = -2.f * cc;
  }
  const bool lowhalf = (l16 < 8);
  const float* xp = x + (size_t)(rb0 + brow) * (S_LEN * DIN);

  float hreg[2] = {0.f, 0.f};  // fp32 h for (brow, j..j+1), register-resident

  // static LDS offsets (shorts)
  const int rd_off = l16 * HPAD + quad * 8;                     // B-frag read (+ kc*32), l16<8
  const int wr_off = brow * HPAD + w * 16 + quad * 4 + rbse;    // dense 4B h' store
  const unsigned short* __restrict__ buf0 = &sh_h[0][0][0];
  unsigned short* __restrict__ buf1 = &sh_h[1][0][0];

  // persistent B-frag regs: zeroed ONCE; lanes l16>=8 never overwrite them
  short8 bf[4];
#pragma unroll
  for (int kc = 0; kc < 4; ++kc) bf[kc] = short8{0, 0, 0, 0, 0, 0, 0, 0};

  // x prefetch: 6 floats per 2-step pair as 3x float2 (24B step-pair stride)
  float2 pfa = *(const float2*)(xp);
  float2 pfb = *(const float2*)(xp + 2);
  float2 pfc = *(const float2*)(xp + 4);

  __syncthreads();

  auto do_step = [&](const unsigned short* __restrict__ cur,
                     unsigned short* __restrict__ nxt,
                     float xc0, float xc1, float xc2) {
    // B-fragments of h^T (masked; lanes >=8 keep zeros)
    if (l16 < NROWS) {
#pragma unroll
      for (int kc = 0; kc < 4; ++kc)
        bf[kc] = *(const short8*)(cur + rd_off + kc * 32);
    }

    // x-projection terms for this lane's 2 elems (hidden under ds_read latency)
    float t0 = __builtin_fmaf(xc2, ewx[0][2], ebh[0]);
    t0 = __builtin_fmaf(xc1, ewx[0][1], t0);
    t0 = __builtin_fmaf(xc0, ewx[0][0], t0);
    float t1 = __builtin_fmaf(xc2, ewx[1][2], ebh[1]);
    t1 = __builtin_fmaf(xc1, ewx[1][1], t1);
    t1 = __builtin_fmaf(xc0, ewx[1][0], t1);

    // single 4-deep MFMA chain (plain bf16 W)
    f32x4 ah = {0.f, 0.f, 0.f, 0.f};
#pragma unroll
    for (int kc = 0; kc < 4; ++kc)
      ah = __builtin_amdgcn_mfma_f32_16x16x32_bf16(wa[kc], bf[kc], ah, 0, 0, 0);

    // DPP pair-exchange: partner lanes (l16>=8) receive r=2,3 from lane l16-8
    float d2 = dpp_xor8(ah[2]);
    float d3 = dpp_xor8(ah[3]);
    float pre0 = lowhalf ? ah[0] : d2;
    float pre1 = lowhalf ? ah[1] : d3;

    // dense epilogue: 2 elems/lane, every lane
    {
      float e  = __builtin_amdgcn_exp2f(pre0 + t0);
      float rc = __builtin_amdgcn_rcpf(e + 1.f);
      hreg[0] = __builtin_fmaf(encc2[0], rc, __builtin_fmaf(hreg[0], ea[0], ecc[0]));
    }
    {
      float e  = __builtin_amdgcn_exp2f(pre1 + t1);
      float rc = __builtin_amdgcn_rcpf(e + 1.f);
      hreg[1] = __builtin_fmaf(encc2[1], rc, __builtin_fmaf(hreg[1], ea[1], ecc[1]));
    }

    *(unsigned int*)(nxt + wr_off) = pack2_bf16(hreg[0], hreg[1]);  // dense 4B store
    __syncthreads();
  };

  for (int s = 0; s < S_LEN; s += 2) {
    float2 xa = pfa, xb = pfb, xc = pfc;
    if (s + 2 < S_LEN) {           // uniform branch; prefetch next pair
      xp += 6;
      pfa = *(const float2*)(xp);
      pfb = *(const float2*)(xp + 2);
      pfc = *(const float2*)(xp + 4);
    }
    do_step(buf0, buf1, xa.x, xa.y, xb.x);
    do_step(buf1, (unsigned short*)buf0, xb.y, xc.x, xc.y);
  }

  // ---- final head: params = softplus(h @ fc_W^T + fc_b), [8 x 6] per block ----
  {
    float2 v = make_float2(hreg[0], hreg[1]);
    *(float2*)&sh_p[brow][w * 16 + quad * 4 + rbse] = v;   // 8B-aligned, all lanes distinct
  }
  __syncthreads();

  if (tid < NROWS * DOUT) {
    const int b = tid / DOUT;
    const int o = tid - b * DOUT;
    const float* fw = fc_W + o * H;
    float acc = fc_b[o];
#pragma unroll 4
    for (int k = 0; k < H; ++k) acc += sh_p[b][k] * fw[k];
    float sp = (acc > 15.f) ? acc : logf(1.f + expf(acc));
    out[(rb0 + b) * DOUT + o] = sp;
  }
}

extern "C" void kernel_launch(void* const* d_in, const int* in_sizes, int n_in,
                              void* d_out, int out_size, void* d_ws, size_t ws_size,
                              hipStream_t stream) {
  const float* x       = (const float*)d_in[0];
  const float* W_xh    = (const float*)d_in[1];
  const float* W_hh    = (const float*)d_in[2];
  const float* b_hh    = (const float*)d_in[3];
  const float* log_tau = (const float*)d_in[4];
  const float* fc_W    = (const float*)d_in[5];
  const float* fc_b    = (const float*)d_in[6];
  float* out           = (float*)d_out;

  ltc_kernel<<<dim3(B_TOT / NROWS), dim3(512), 0, stream>>>(
      x, W_xh, W_hh, b_hh, log_tau, fc_W, fc_b, out);
}